// Round 7
// baseline (691.524 us; speedup 1.0000x reference)
//
#include <hip/hip_runtime.h>
#include <hip/hip_bf16.h>

// LSTM B=4096 T=512 IN=14 H=28 OUT=2, fp32 in/out.
// R7: minimal serial chain. Per wave: 16 batches, whole recurrence in regs.
// Per 4-step chunk (all OFF the serial chain):
//   - x chunk staged regs->LDS (prefetched one chunk ahead, HBM hidden)
//   - xg[tt][mt] = Wih_perm @ x_tt + bias via 28 INDEPENDENT MFMAs -> 112 VGPRs
// Per step (the serial chain):
//   - 7 independent mfma_f32_16x16x32_bf16 (A=Whh_perm, B=hfrag, C=xg)
//   - phase-major combine (28 exps || ... || 7 rcps) -> ILP across units
//   - pack hn -> hfrag (identity placement: unit q*7+mt == B-slot k=q*8+mt)
// No LDS/barrier in the step. Weights pre-scaled by -log2(e) (g: -2log2(e)).
// 256 single-wave blocks; wall = 512 x per-step chain.

#define T_STEPS 512
#define BATCH   4096
#define IN_F    14
#define HID     28
#define OUT_N   2
#define WB      16
#define TC      4
#define NCHUNK  (T_STEPS / TC)     // 128
#define XPIT    68                 // LDS floats per batch row (4m%32 -> 2-way, free)

typedef __attribute__((ext_vector_type(8))) short  short8;
typedef __attribute__((ext_vector_type(4))) float  float4v;

#define L1 1.4426950408889634f     // log2(e)

__device__ __forceinline__ int pk2(float a, float b) {   // bf16(a) | bf16(b)<<16
    __hip_bfloat162 t = __float22bfloat162_rn(float2{a, b});
    union { __hip_bfloat162 h; int i; } u; u.h = t; return u.i;
}

union S8 { int i[4]; short8 s; };

__global__ __launch_bounds__(64, 1)
void lstm_reg2(const float* __restrict__ x,
               const float* __restrict__ W_ih,
               const float* __restrict__ W_hh,
               const float* __restrict__ b_ih,
               const float* __restrict__ b_hh,
               const float* __restrict__ W_out,
               const float* __restrict__ b_out,
               float* __restrict__ out) {
    __shared__ __align__(16) float xs[WB][XPIT];   // 4.35 KB x chunk

    const int l  = threadIdx.x;
    const int q  = l >> 4;           // 0..3
    const int m  = l & 15;           // batch column / A-row
    const int b0 = blockIdx.x * WB;

    // ---- A-fragments (Wperm, pre-scaled, bf16) + scaled bias (verified R6) ----
    short8  wa0[7], wa1[7];          // wa0 = h-cols, wa1 = x-cols
    float4v biasv[7];
    #pragma unroll
    for (int mt = 0; mt < 7; ++mt) {
        const int r    = m & 3;
        const int uu   = (m >> 2) * 7 + mt;
        const int orow = r * HID + uu;
        const float sc = (r == 2) ? (-2.0f * L1) : (-L1);
        S8 v0, v1;
        #pragma unroll
        for (int jj = 0; jj < 4; ++jj) {
            int j0 = 2 * jj, j1 = 2 * jj + 1;
            float wh0 = (j0 < 7) ? W_hh[orow * HID + (q * 7 + j0)] * sc : 0.0f;
            float wh1 = (j1 < 7) ? W_hh[orow * HID + (q * 7 + j1)] * sc : 0.0f;
            v0.i[jj] = pk2(wh0, wh1);
            int f0 = q * 8 + j0, f1 = q * 8 + j1;
            float wx0 = (f0 < IN_F) ? W_ih[orow * IN_F + f0] * sc : 0.0f;
            float wx1 = (f1 < IN_F) ? W_ih[orow * IN_F + f1] * sc : 0.0f;
            v1.i[jj] = pk2(wx0, wx1);
        }
        wa0[mt] = v0.s; wa1[mt] = v1.s;
        float4v bv;
        #pragma unroll
        for (int rr = 0; rr < 4; ++rr) {
            const int br = rr * HID + (q * 7 + mt);
            const float s2 = (rr == 2) ? (-2.0f * L1) : (-L1);
            bv[rr] = (b_ih[br] + b_hh[br]) * s2;
        }
        biasv[mt] = bv;
    }

    // ---- zero LDS once (pads stay 0 forever; staging writes only 0..55) ----
    for (int u = l; u < WB * XPIT; u += 64) ((float*)xs)[u] = 0.0f;

    // ---- staging geometry: chunk = 16 batches x 56 floats = 224 float4 ----
    int sb[4], sp[4];                // lane-constant (b, float4-pos) per k
    #pragma unroll
    for (int k = 0; k < 4; ++k) {
        const int idx = l + 64 * k;
        sb[k] = idx / 14; sp[k] = idx % 14;
    }

    // prefetch chunk 0 into regs
    float4 sreg[4];
    #pragma unroll
    for (int k = 0; k < 4; ++k)
        if (l + 64 * k < 224)
            sreg[k] = *(const float4*)(x + (long)(b0 + sb[k]) * (T_STEPS * IN_F)
                                         + sp[k] * 4);

    // ---- state ----
    short8 hfrag = {0, 0, 0, 0, 0, 0, 0, 0};
    float  cc[7] = {0, 0, 0, 0, 0, 0, 0};
    float  hn[7] = {0, 0, 0, 0, 0, 0, 0};

    for (int ch = 0; ch < NCHUNK; ++ch) {
        // ---- staged regs -> LDS ----
        __syncthreads();                      // xs free (prev chunk consumed)
        #pragma unroll
        for (int k = 0; k < 4; ++k)
            if (l + 64 * k < 224)
                *(float4*)&xs[sb[k]][sp[k] * 4] = sreg[k];
        __syncthreads();

        // ---- xg[tt][mt]: 28 independent MFMAs, bias as C-init ----
        float4v xg[TC][7];
        #pragma unroll
        for (int tt = 0; tt < TC; ++tt) {
            const int off = (q < 2) ? (tt * IN_F + q * 8) : 0;
            float4 xa = *(const float4*)&xs[m][off];
            float4 xb = *(const float4*)&xs[m][off + 4];
            S8 xf;
            xf.i[0] = pk2(xa.x, xa.y); xf.i[1] = pk2(xa.z, xa.w);
            xf.i[2] = pk2(xb.x, xb.y); xf.i[3] = pk2(xb.z, xb.w);
            #pragma unroll
            for (int mt = 0; mt < 7; ++mt)
                xg[tt][mt] = __builtin_amdgcn_mfma_f32_16x16x32_bf16(wa1[mt], xf.s, biasv[mt], 0, 0, 0);
        }

        // ---- issue next chunk's global loads (hidden under 4 steps) ----
        if (ch + 1 < NCHUNK) {
            #pragma unroll
            for (int k = 0; k < 4; ++k)
                if (l + 64 * k < 224)
                    sreg[k] = *(const float4*)(x + (long)(b0 + sb[k]) * (T_STEPS * IN_F)
                                                 + (ch + 1) * (TC * IN_F) + sp[k] * 4);
        }

        // ---- serial recurrence: 4 steps ----
        #pragma unroll
        for (int tt = 0; tt < TC; ++tt) {
            float4v a[7];
            #pragma unroll
            for (int mt = 0; mt < 7; ++mt)
                a[mt] = __builtin_amdgcn_mfma_f32_16x16x32_bf16(wa0[mt], hfrag, xg[tt][mt], 0, 0, 0);

            // phase-major combine (ILP across the 7 units)
            float e0[7], e1[7], e2[7], e3[7];
            #pragma unroll
            for (int mt = 0; mt < 7; ++mt) e0[mt] = __builtin_amdgcn_exp2f(a[mt][0]);
            #pragma unroll
            for (int mt = 0; mt < 7; ++mt) e1[mt] = __builtin_amdgcn_exp2f(a[mt][1]);
            #pragma unroll
            for (int mt = 0; mt < 7; ++mt) e2[mt] = __builtin_amdgcn_exp2f(a[mt][2]);
            #pragma unroll
            for (int mt = 0; mt < 7; ++mt) e3[mt] = __builtin_amdgcn_exp2f(a[mt][3]);
            float rv[7], pd[7];
            #pragma unroll
            for (int mt = 0; mt < 7; ++mt) {
                pd[mt] = (1.0f + e0[mt]) * (1.0f + e2[mt]);
                rv[mt] = __builtin_amdgcn_rcpf(pd[mt] * (1.0f + e1[mt]));
            }
            #pragma unroll
            for (int mt = 0; mt < 7; ++mt) {
                float sf = pd[mt] * rv[mt];                            // sigma(f)
                float ig = (1.0f - e2[mt]) * (1.0f + e1[mt]) * rv[mt]; // sig(i)*tanh(g)
                cc[mt] = fmaf(sf, cc[mt], ig);
            }
            float ec[7];
            #pragma unroll
            for (int mt = 0; mt < 7; ++mt)
                ec[mt] = __builtin_amdgcn_exp2f(cc[mt] * (-2.0f * L1));
            #pragma unroll
            for (int mt = 0; mt < 7; ++mt) {
                float r2 = __builtin_amdgcn_rcpf((1.0f + e3[mt]) * (1.0f + ec[mt]));
                hn[mt] = (1.0f - ec[mt]) * r2;                         // sig(o)*tanh(c)
            }

            // pack h -> next B-fragment (identity placement)
            S8 hf;
            hf.i[0] = pk2(hn[0], hn[1]); hf.i[1] = pk2(hn[2], hn[3]);
            hf.i[2] = pk2(hn[4], hn[5]); hf.i[3] = pk2(hn[6], 0.0f);
            hfrag = hf.s;
        }
    }

    // ---- epilogue: out[b][o] = sum_u h[u]*W_out[o][u] + b_out[o] ----
    float po[OUT_N];
    #pragma unroll
    for (int o = 0; o < OUT_N; ++o) {
        float sacc = 0.0f;
        #pragma unroll
        for (int mt = 0; mt < 7; ++mt)
            sacc = fmaf(hn[mt], W_out[o * HID + (q * 7 + mt)], sacc);
        sacc += __shfl_xor(sacc, 16, 64);
        sacc += __shfl_xor(sacc, 32, 64);
        po[o] = sacc;
    }
    if (l < WB) {
        out[(b0 + m) * OUT_N + 0] = po[0] + b_out[0];
        out[(b0 + m) * OUT_N + 1] = po[1] + b_out[1];
    }
}

extern "C" void kernel_launch(void* const* d_in, const int* in_sizes, int n_in,
                              void* d_out, int out_size, void* d_ws, size_t ws_size,
                              hipStream_t stream) {
    const float* x     = (const float*)d_in[0];
    const float* W_ih  = (const float*)d_in[1];
    const float* W_hh  = (const float*)d_in[2];
    const float* b_ih  = (const float*)d_in[3];
    const float* b_hh  = (const float*)d_in[4];
    const float* W_out = (const float*)d_in[5];
    const float* b_out = (const float*)d_in[6];
    float* out = (float*)d_out;

    lstm_reg2<<<BATCH / WB, 64, 0, stream>>>(
        x, W_ih, W_hh, b_ih, b_hh, W_out, b_out, out);
}

// Round 8
// 629.313 us; speedup vs baseline: 1.0989x; 1.0989x over previous
//
#include <hip/hip_runtime.h>
#include <hip/hip_bf16.h>

// LSTM B=4096 T=512 IN=14 H=28 OUT=2, fp32 in/out.
// R8 = R6 structure, spill-proof + chain-minimal:
//  - Orientation D = Wperm @ [h;x] (verified R6/R7): lane (q,m) owns units
//    u=q*7+mt (all 4 gates in acc rows) for batch m; new h lands exactly in
//    this lane's B-slot k=q*8+mt -> in-register recurrence, no LDS on chain.
//  - Per step: 7 x-MFMAs (C=bias, off-chain) then 7 h-MFMAs (the chain),
//    phase-major combine (ILP across 7 units), pack hfrag.
//  - x staged per 32-step chunk into LDS ALREADY PACKED as bf16 pairs
//    (8 ints per (b,t), row pitch 260 ints -> 2-way banks, 16B aligned);
//    per-step x = one ds_read_b128, prefetched one step ahead.
//  - NO xg array (R7's spill cause). Peak live regs ~200.
// Grid 256 x 64thr; wall = 512 x per-step chain of one wave.

#define T_STEPS 512
#define BATCH   4096
#define IN_F    14
#define HID     28
#define OUT_N   2
#define WB      16
#define TC      32                  // timesteps per chunk
#define NCHUNK  (T_STEPS / TC)      // 16
#define RPIT    260                 // ints per batch row (260%32=4 -> 2-way)

typedef __attribute__((ext_vector_type(8))) short  short8;
typedef __attribute__((ext_vector_type(4))) float  float4v;

#define L1 1.4426950408889634f      // log2(e)

__device__ __forceinline__ int pk2(float a, float b) {   // bf16(a) | bf16(b)<<16
    __hip_bfloat162 t = __float22bfloat162_rn(float2{a, b});
    union { __hip_bfloat162 h; int i; } u; u.h = t; return u.i;
}

union S8 { int i[4]; short8 s; };

__global__ __launch_bounds__(64, 1)
void lstm_reg3(const float* __restrict__ x,
               const float* __restrict__ W_ih,
               const float* __restrict__ W_hh,
               const float* __restrict__ b_ih,
               const float* __restrict__ b_hh,
               const float* __restrict__ W_out,
               const float* __restrict__ b_out,
               float* __restrict__ out) {
    __shared__ __align__(16) int xpk[WB][RPIT];   // packed bf16 x chunk (16.6 KB)

    const int l  = threadIdx.x;
    const int q  = l >> 4;            // 0..3
    const int m  = l & 15;            // batch column / A-row
    const int b0 = blockIdx.x * WB;

    // ---- A-fragments (Wperm, pre-scaled by -log2e, g-gate -2log2e) + bias ----
    short8  wa0[7], wa1[7];           // h-cols / x-cols
    float4v biasv[7];
    #pragma unroll
    for (int mt = 0; mt < 7; ++mt) {
        const int r    = m & 3;
        const int uu   = (m >> 2) * 7 + mt;
        const int orow = r * HID + uu;
        const float sc = (r == 2) ? (-2.0f * L1) : (-L1);
        S8 v0, v1;
        #pragma unroll
        for (int jj = 0; jj < 4; ++jj) {
            int j0 = 2 * jj, j1 = 2 * jj + 1;
            float wh0 = (j0 < 7) ? W_hh[orow * HID + (q * 7 + j0)] * sc : 0.0f;
            float wh1 = (j1 < 7) ? W_hh[orow * HID + (q * 7 + j1)] * sc : 0.0f;
            v0.i[jj] = pk2(wh0, wh1);
            int f0 = q * 8 + j0, f1 = q * 8 + j1;
            float wx0 = (f0 < IN_F) ? W_ih[orow * IN_F + f0] * sc : 0.0f;
            float wx1 = (f1 < IN_F) ? W_ih[orow * IN_F + f1] * sc : 0.0f;
            v1.i[jj] = pk2(wx0, wx1);
        }
        wa0[mt] = v0.s; wa1[mt] = v1.s;
        float4v bv;
        #pragma unroll
        for (int rr = 0; rr < 4; ++rr) {
            const int br = rr * HID + (q * 7 + mt);
            const float s2 = (rr == 2) ? (-2.0f * L1) : (-L1);
            bv[rr] = (b_ih[br] + b_hh[br]) * s2;
        }
        biasv[mt] = bv;
    }

    // ---- zero LDS once (j==7 slots + pad stay 0 forever) ----
    for (int u = l; u < WB * RPIT; u += 64) ((int*)xpk)[u] = 0;

    // ---- state ----
    short8 hfrag = {0, 0, 0, 0, 0, 0, 0, 0};
    float  cc[7] = {0, 0, 0, 0, 0, 0, 0};
    float  hn[7] = {0, 0, 0, 0, 0, 0, 0};

    const int xoff = m * RPIT + (q & 1) * 4;   // per-lane read base (ints)

    for (int ch = 0; ch < NCHUNK; ++ch) {
        // ---- stage chunk: 28 coalesced float4 loads -> packed bf16 LDS ----
        __syncthreads();
        #pragma unroll
        for (int k = 0; k < 28; ++k) {
            const int idx = l + 64 * k;            // 0..1791 float4s
            const int b   = idx / 112;             // 112 float4 per batch-chunk
            const int p   = idx - b * 112;
            float4 v = *(const float4*)(x + (long)(b0 + b) * (T_STEPS * IN_F)
                                          + ch * (TC * IN_F) + 4 * p);
            const int g0 = 2 * p, g1 = 2 * p + 1;  // int indices (7 per t)
            xpk[b][(g0 / 7) * 8 + (g0 % 7)] = pk2(v.x, v.y);
            xpk[b][(g1 / 7) * 8 + (g1 % 7)] = pk2(v.z, v.w);
        }
        __syncthreads();

        int4 xf_cur = *(const int4*)&xpk[0][xoff];           // tt = 0
        #pragma unroll 8
        for (int tt = 0; tt < TC; ++tt) {
            // prefetch next step's x fragment (off-chain)
            const int tn = (tt + 1 < TC) ? tt + 1 : tt;
            int4 xf_nxt = *(const int4*)&xpk[0][xoff + tn * 8];

            S8 xf; xf.i[0] = xf_cur.x; xf.i[1] = xf_cur.y;
                   xf.i[2] = xf_cur.z; xf.i[3] = xf_cur.w;

            // 7 x-MFMAs (independent of h), then 7 chain MFMAs
            float4v a[7];
            #pragma unroll
            for (int mt = 0; mt < 7; ++mt)
                a[mt] = __builtin_amdgcn_mfma_f32_16x16x32_bf16(wa1[mt], xf.s, biasv[mt], 0, 0, 0);
            #pragma unroll
            for (int mt = 0; mt < 7; ++mt)
                a[mt] = __builtin_amdgcn_mfma_f32_16x16x32_bf16(wa0[mt], hfrag, a[mt], 0, 0, 0);

            // phase-major combine (ILP across the 7 units)
            float e0[7], e1[7], e2[7], e3[7];
            #pragma unroll
            for (int mt = 0; mt < 7; ++mt) e0[mt] = __builtin_amdgcn_exp2f(a[mt][0]);
            #pragma unroll
            for (int mt = 0; mt < 7; ++mt) e1[mt] = __builtin_amdgcn_exp2f(a[mt][1]);
            #pragma unroll
            for (int mt = 0; mt < 7; ++mt) e2[mt] = __builtin_amdgcn_exp2f(a[mt][2]);
            #pragma unroll
            for (int mt = 0; mt < 7; ++mt) e3[mt] = __builtin_amdgcn_exp2f(a[mt][3]);
            float pd[7], rv[7];
            #pragma unroll
            for (int mt = 0; mt < 7; ++mt) {
                pd[mt] = (1.0f + e0[mt]) * (1.0f + e2[mt]);
                rv[mt] = __builtin_amdgcn_rcpf(pd[mt] * (1.0f + e1[mt]));
            }
            #pragma unroll
            for (int mt = 0; mt < 7; ++mt) {
                float sf = pd[mt] * rv[mt];                            // sigma(f)
                float ig = (1.0f - e2[mt]) * (1.0f + e1[mt]) * rv[mt]; // sig(i)*tanh(g)
                cc[mt] = fmaf(sf, cc[mt], ig);
            }
            float ec[7];
            #pragma unroll
            for (int mt = 0; mt < 7; ++mt)
                ec[mt] = __builtin_amdgcn_exp2f(cc[mt] * (-2.0f * L1));
            #pragma unroll
            for (int mt = 0; mt < 7; ++mt) {
                float r2 = __builtin_amdgcn_rcpf((1.0f + e3[mt]) * (1.0f + ec[mt]));
                hn[mt] = (1.0f - ec[mt]) * r2;                         // sig(o)*tanh(c)
            }

            // pack h -> next B-fragment (identity placement)
            S8 hf;
            hf.i[0] = pk2(hn[0], hn[1]); hf.i[1] = pk2(hn[2], hn[3]);
            hf.i[2] = pk2(hn[4], hn[5]); hf.i[3] = pk2(hn[6], 0.0f);
            hfrag = hf.s;
            xf_cur = xf_nxt;
        }
    }

    // ---- epilogue: out[b][o] = sum_u h[u]*W_out[o][u] + b_out[o] ----
    float po[OUT_N];
    #pragma unroll
    for (int o = 0; o < OUT_N; ++o) {
        float sacc = 0.0f;
        #pragma unroll
        for (int mt = 0; mt < 7; ++mt)
            sacc = fmaf(hn[mt], W_out[o * HID + (q * 7 + mt)], sacc);
        sacc += __shfl_xor(sacc, 16, 64);
        sacc += __shfl_xor(sacc, 32, 64);
        po[o] = sacc;
    }
    if (l < WB) {
        out[(b0 + m) * OUT_N + 0] = po[0] + b_out[0];
        out[(b0 + m) * OUT_N + 1] = po[1] + b_out[1];
    }
}

extern "C" void kernel_launch(void* const* d_in, const int* in_sizes, int n_in,
                              void* d_out, int out_size, void* d_ws, size_t ws_size,
                              hipStream_t stream) {
    const float* x     = (const float*)d_in[0];
    const float* W_ih  = (const float*)d_in[1];
    const float* W_hh  = (const float*)d_in[2];
    const float* b_ih  = (const float*)d_in[3];
    const float* b_hh  = (const float*)d_in[4];
    const float* W_out = (const float*)d_in[5];
    const float* b_out = (const float*)d_in[6];
    float* out = (float*)d_out;

    lstm_reg3<<<BATCH / WB, 64, 0, stream>>>(
        x, W_ih, W_hh, b_ih, b_hh, W_out, b_out, out);
}